// Round 1
// 194.516 us; speedup vs baseline: 1.0653x; 1.0653x over previous
//
#include <hip/hip_runtime.h>

#define N_PTS 50000
#define M 32
#define KP 15
#define D 64
#define E1 45
#define P 8
#define WFS 1048   // wfh plane row stride (ushorts): >=1024 enum slots

typedef __attribute__((ext_vector_type(8))) _Float16 f16x8;
typedef __attribute__((ext_vector_type(4))) float    f32x4;
typedef __attribute__((ext_vector_type(2))) _Float16 f16x2;
typedef __attribute__((ext_vector_type(2))) __fp16   fp16v2;   // builtin return type

__device__ __forceinline__ unsigned pkrtz(float a, float b) {   // packed fp16 RTZ
    union { fp16v2 v; unsigned u; } x;
    x.v = __builtin_amdgcn_cvt_pkrtz(a, b);
    return x.u;
}
__device__ __forceinline__ unsigned pkrne(float a, float b) {   // packed fp16 RNE
    union { f16x2 v; unsigned u; } x;
    x.v[0] = (_Float16)a; x.v[1] = (_Float16)b; return x.u;
}
__device__ __forceinline__ float h2f(unsigned bits16) {
    union { unsigned short s; _Float16 h; } x; x.s = (unsigned short)bits16;
    return (float)x.h;
}
// compensated fp16 split of a pair: hu = packed hi (RTZ), lu = packed residual
__device__ __forceinline__ void split2h(float a, float b, unsigned& hu, unsigned& lu) {
    hu = pkrtz(a, b);
    const float ra = a - h2f(hu & 0xffffu);
    const float rb = b - h2f(hu >> 16);
    lu = pkrtz(ra, rb);
}
// packed single value split: lo16 = fp16 hi (RNE), hi16 = fp16 residual
__device__ __forceinline__ unsigned splitpk1(float v) {
    const _Float16 h = (_Float16)v;
    const _Float16 l = (_Float16)(v - (float)h);
    union { f16x2 v2; unsigned u; } x; x.v2[0] = h; x.v2[1] = l; return x.u;
}

#if defined(__HIP_DEVICE_COMPILE__) && __has_builtin(__builtin_amdgcn_perm)
__device__ __forceinline__ unsigned permb(unsigned a, unsigned b, unsigned sel) {
    return __builtin_amdgcn_perm(a, b, sel);
}
#else
__device__ __forceinline__ unsigned permb(unsigned a, unsigned b, unsigned sel) {
    if (sel == 0x05040100u) return (b & 0xffffu) | (a << 16);
    return (b >> 16) | (a & 0xffff0000u);
}
#endif

// ---------------- fused prep (one launch; writes d_ws) -----------------------
// blocks [0,3125): x -> packed {f16 hi, f16 residual} dwords (float4/uint4 vectorized)
// blocks [3125,3317): ow -> owh/owl fp16 planes; pos swizzle:
//     orig = pos ^ (((pos>>6)&3)<<2); d = orig>>4, k = orig&15 (zero pad k==15/e>=45)
// blocks [3317,3557): w -> wh single fp16 plane; pos = k*64+dsw, d = dsw ^ ((k&7)<<3)
__global__ void prep_all(const float* __restrict__ x, const float* __restrict__ ow,
                         const float* __restrict__ w, unsigned* __restrict__ xw,
                         unsigned short* __restrict__ owh, unsigned short* __restrict__ owl,
                         unsigned short* __restrict__ wh)
{
    const int b = blockIdx.x, tid = threadIdx.x;
    if (b < 3125) {
        const int i = b * 256 + tid;
        const float4 v = ((const float4*)x)[i];
        uint4 u;
        u.x = splitpk1(v.x); u.y = splitpk1(v.y);
        u.z = splitpk1(v.z); u.w = splitpk1(v.w);
        ((uint4*)xw)[i] = u;
    } else if (b < 3317) {
        const int t = (b - 3125) * 256 + tid;               // [0, 49152)
        const int j = t & 7, lane = (t >> 3) & 63, rest = t >> 9;
        const int nt = rest % 3, ks = rest / 3;
        const int q = lane >> 4, c = lane & 15;
        const int pos  = ks * 32 + q * 8 + j;
        const int orig = pos ^ (((pos >> 6) & 3) << 2);
        const int d = orig >> 4, k = orig & 15, e = nt * 16 + c;
        const float v = (k < KP && e < E1) ? ow[k * (D * E1) + d * E1 + e] : 0.f;
        const unsigned u = splitpk1(v);
        owh[t] = (unsigned short)u;
        owl[t] = (unsigned short)(u >> 16);
    } else {
        const int t = (b - 3317) * 256 + tid;               // [0, 61440)
        const int j = t & 7, lane = (t >> 3) & 63, rest = t >> 9;
        const int nt = rest & 3, ks = rest >> 2;            // ks in [0,30)
        const int q = lane >> 4, c = lane & 15;
        const int pos = ks * 32 + q * 8 + j;                // [0,960)
        const int k = pos >> 6, dsw = pos & 63;
        const int d = dsw ^ ((k & 7) << 3);
        const int e = nt * 16 + c;
        union { _Float16 h; unsigned short s; } cv;
        cv.h = (_Float16)w[k * (D * D) + d * D + e];        // RNE single fp16
        wh[t] = cv.s;
    }
}

__global__ __launch_bounds__(256, 4) void kpconv_deform(
    const float* __restrict__ qpts, const float* __restrict__ spts,
    const int*   __restrict__ nbrs, const float* __restrict__ kpts,
    const float* __restrict__ obias,
    const unsigned* __restrict__ xw,
    const unsigned short* __restrict__ owh, const unsigned short* __restrict__ owl,
    const unsigned short* __restrict__ wh,
    float* __restrict__ out)
{
    __shared__ int   s_nbr[P][M];
    __shared__ float s_kp[KP][3];
    __shared__ float s_q[P][3];
    __shared__ float s_off[P][E1];
    __shared__ unsigned s_act[4];
    // wfh plane: ph2->ph3 compensated-hi pair enum (1024); ph6->ph7 single, k*64+dsw
    __shared__ __align__(16) unsigned short s_wfh[P][WFS];
    // bufB quadruple-use (all transitions wave-private per point or barrier-fenced):
    //   ph1->ph2: aw pair planes, per-point interleaved  s_aw[p][0]=hi, s_aw[p][1]=lo
    //   ph2->ph3: wfl residual plane, per-point 1024 slots at p*1024 (ushort idx),
    //             XOR-swizzled by (p&7)<<3 for conflict-free per-lane-pr reads
    //   ph3->red: s_part3 partials (after an in-ph3 barrier — wfl dead by then)
    //   ph5->ph6: aw hi plane (s_aw[p][0])
    __shared__ __align__(16) char s_bufB[16384];
    unsigned short (*s_aw)[2][512] = (unsigned short(*)[2][512])s_bufB;
    unsigned short *s_wflp = (unsigned short*)s_bufB;
    float (*s_part3)[16][49] = (float(*)[16][49])s_bufB;                    // 12544 B

    const int tid  = threadIdx.x;
    const int base = blockIdx.x * P;
    const int lane = tid & 63;
    const int wid  = tid >> 6;
    const int q    = lane >> 4, c = lane & 15;
    const int pg   = tid >> 5, mg = tid & 31;   // (p,m) mapping for ph1/ph5
    // wave w's ph1/ph5 points {2w,2w+1} == its ph2/ph6 consumers -> no barrier needed

    float nbx, nby, nbz;   // centered neighbor coords, live ph1->ph5
    f16x8 fbh[2][4];       // cached x hi fragments (ph2 -> ph6)

    if (tid < KP * 3) ((float*)s_kp)[tid] = kpts[tid];
    if (tid < P * 3)  ((float*)s_q)[tid]  = qpts[base * 3 + tid];
    __syncthreads();

    // ---- ph1: gather, centered nb, aw1 -> compensated fp16 planes [p][k*32+m] ----
    {
        const int ni = nbrs[(base + pg) * M + mg];
        s_nbr[pg][mg] = ni;
        nbx = spts[ni * 3 + 0] - s_q[pg][0];
        nby = spts[ni * 3 + 1] - s_q[pg][1];
        nbz = spts[ni * 3 + 2] - s_q[pg][2];
        float av[16];
        av[15] = 0.f;                               // pad row -> exact zeros
#pragma unroll
        for (int k = 0; k < KP; k++) {
            const float dx = nbx - s_kp[k][0];
            const float dy = nby - s_kp[k][1];
            const float dz = nbz - s_kp[k][2];
            av[k] = fmaxf(1.0f - sqrtf(dx * dx + dy * dy + dz * dz), 0.f);
        }
#pragma unroll
        for (int k2 = 0; k2 < 16; k2 += 2) {
            unsigned hu, lu; split2h(av[k2], av[k2 + 1], hu, lu);
            s_aw[pg][0][k2 * 32 + mg]       = (unsigned short)hu;
            s_aw[pg][0][(k2 + 1) * 32 + mg] = (unsigned short)(hu >> 16);
            s_aw[pg][1][k2 * 32 + mg]       = (unsigned short)lu;
            s_aw[pg][1][(k2 + 1) * 32 + mg] = (unsigned short)(lu >> 16);
        }
    }
    // no barrier: ph2 wave reads only its own writes (lgkmcnt ordering)

    // ---- ph2: wf1 via compensated f16 MFMA; cache x hi fragments ----
    // NOTE: aw[p] reads precede wfl[p] writes (same region, same wave, program
    // order preserved by may-alias LDS ops) -> safe in-place reuse.
    {
        const int hc = c >> 2;
#pragma unroll
        for (int pi = 0; pi < 2; pi++) {
            const int p = 2 * wid + pi;
            const int pswz = p << 3;
            const f16x8 ah = *(const f16x8*)&s_aw[p][0][(lane & 15) * 32 + q * 8];
            const f16x8 al = *(const f16x8*)&s_aw[p][1][(lane & 15) * 32 + q * 8];
            int nbj[8];
#pragma unroll
            for (int j = 0; j < 8; j++) nbj[j] = s_nbr[p][q * 8 + j];
#pragma unroll
            for (int t = 0; t < 4; t++) {
                unsigned g[8];
#pragma unroll
                for (int j = 0; j < 8; j++)
                    g[j] = xw[nbj[j] * D + t * 16 + c];
                union { f16x8 v; unsigned u[4]; } bh, bl;
#pragma unroll
                for (int jj = 0; jj < 4; jj++) {    // perm-unpack hi/lo planes
                    bh.u[jj] = permb(g[2 * jj + 1], g[2 * jj], 0x05040100u);
                    bl.u[jj] = permb(g[2 * jj + 1], g[2 * jj], 0x07060302u);
                }
                fbh[pi][t] = bh.v;                   // cache hi for ph6
                f32x4 dacc = {0.f, 0.f, 0.f, 0.f};
                dacc = __builtin_amdgcn_mfma_f32_16x16x32_f16(ah, bh.v, dacc, 0, 0, 0);
                dacc = __builtin_amdgcn_mfma_f32_16x16x32_f16(ah, bl.v, dacc, 0, 0, 0);
                dacc = __builtin_amdgcn_mfma_f32_16x16x32_f16(al, bh.v, dacc, 0, 0, 0);
                unsigned h01, l01, h23, l23;
                split2h(dacc[0], dacc[1], h01, l01);
                split2h(dacc[2], dacc[3], h23, l23);
                // swizzled enum: pos = (t*16+c)*16 + 4*(q^hc) (+r)
                const int eb = (t * 16 + c) * 16 + 4 * (q ^ hc);
                *(uint2*)&s_wfh[p][eb] = make_uint2(h01, h23);
                *(uint2*)&s_wflp[p * 1024 + (eb ^ pswz)] = make_uint2(l01, l23);
            }
        }
    }
    __syncthreads();

    // ---- ph3: offsets via compensated f16 MFMA, contraction split over 4 waves ----
    {
        const int pr = lane & 7;                     // A rows 8..15 duplicate points 0..7
        const int prswz = pr << 3;
        f32x4 acc0 = {0,0,0,0}, acc1 = {0,0,0,0}, acc2 = {0,0,0,0};
#pragma unroll
        for (int s = 0; s < 8; s++) {
            const int ks = wid * 8 + s;
            const f16x8 ah = *(const f16x8*)&s_wfh[pr][ks * 32 + q * 8];
            const f16x8 al = *(const f16x8*)&s_wflp[pr * 1024 + ((ks * 32 + q * 8) ^ prswz)];
#pragma unroll
            for (int nt = 0; nt < 3; nt++) {
                const int f = ((ks * 3 + nt) * 64 + lane) * 8;
                const f16x8 bh = *(const f16x8*)&owh[f];
                const f16x8 bl = *(const f16x8*)&owl[f];
                f32x4* acc = (nt == 0) ? &acc0 : (nt == 1) ? &acc1 : &acc2;
                *acc = __builtin_amdgcn_mfma_f32_16x16x32_f16(ah, bh, *acc, 0, 0, 0);
                *acc = __builtin_amdgcn_mfma_f32_16x16x32_f16(ah, bl, *acc, 0, 0, 0);
                *acc = __builtin_amdgcn_mfma_f32_16x16x32_f16(al, bh, *acc, 0, 0, 0);
            }
        }
        __syncthreads();   // wfl (bufB) about to be clobbered by s_part3
#pragma unroll
        for (int r = 0; r < 4; r++) {
            s_part3[wid][4 * q + r][0 * 16 + c] = acc0[r];
            s_part3[wid][4 * q + r][1 * 16 + c] = acc1[r];
            s_part3[wid][4 * q + r][2 * 16 + c] = acc2[r];
        }
    }
    __syncthreads();

    // ---- reduce K-partials + bias -> offsets (fp32) ----
    for (int idx = tid; idx < P * E1; idx += 256) {
        const int p = idx / E1, e = idx % E1;
        s_off[p][e] = s_part3[0][p][e] + s_part3[1][p][e] +
                      s_part3[2][p][e] + s_part3[3][p][e] + obias[e];
    }
    __syncthreads();

    // ---- ph5: aw2 (deformed) -> single fp16 plane (RNE) + joint wave mask ----
    {
        unsigned pmask = 0;
        float av[16];
        av[15] = 0.f;
#pragma unroll
        for (int k = 0; k < KP; k++) {
            const float kx = s_kp[k][0] + s_off[pg][3 * k + 0];
            const float ky = s_kp[k][1] + s_off[pg][3 * k + 1];
            const float kz = s_kp[k][2] + s_off[pg][3 * k + 2];
            const float dx = nbx - kx, dy = nby - ky, dz = nbz - kz;
            av[k] = fmaxf(1.0f - sqrtf(dx * dx + dy * dy + dz * dz), 0.f);
            pmask |= (__ballot(av[k] > 0.f) ? 1u : 0u) << k;   // union of wave's 2 pts
        }
#pragma unroll
        for (int k2 = 0; k2 < 16; k2 += 2) {
            const unsigned hu = pkrne(av[k2], av[k2 + 1]);
            s_aw[pg][0][k2 * 32 + mg]       = (unsigned short)hu;
            s_aw[pg][0][(k2 + 1) * 32 + mg] = (unsigned short)(hu >> 16);
        }
        if (lane == 0) s_act[wid] = pmask;
    }
    // no barrier: ph6 wave reads only its own aw writes; s_act read after next barrier

    // ---- ph6: wf2 via single f16 MFMA, operands swapped (D[d][k]) ----
    {
#pragma unroll
        for (int pi = 0; pi < 2; pi++) {
            const int p = 2 * wid + pi;
            const f16x8 awh_f = *(const f16x8*)&s_aw[p][0][(lane & 15) * 32 + q * 8];
#pragma unroll
            for (int t = 0; t < 4; t++) {
                f32x4 dacc = {0.f, 0.f, 0.f, 0.f};
                dacc = __builtin_amdgcn_mfma_f32_16x16x32_f16(fbh[pi][t], awh_f, dacc, 0, 0, 0);
                // wf2[k=c][d = t*16+4q+r] single fp16 (RNE); dsw keeps 4-runs
                const unsigned u01 = pkrne(dacc[0], dacc[1]);
                const unsigned u23 = pkrne(dacc[2], dacc[3]);
                const int dsw = (t * 16 + 4 * q) ^ ((c & 7) << 3);
                *(uint2*)&s_wfh[p][c * 64 + dsw] = make_uint2(u01, u23);
            }
        }
    }
    __syncthreads();

    const unsigned u2 = s_act[0] | s_act[1] | s_act[2] | s_act[3];

    // ---- ph7: output via single f16 MFMA over active k; wave = e-tile ----
    {
        const int pr = lane & 7;                    // A rows 8..15 duplicate points 0..7
        f32x4 acc = {0.f, 0.f, 0.f, 0.f};
#pragma unroll
        for (int k = 0; k < KP; k++) {
            if (!((u2 >> k) & 1)) continue;
#pragma unroll
            for (int kk = 0; kk < 2; kk++) {
                const int ks = k * 2 + kk;          // pos chunk: k = ks>>1
                const f16x8 ah = *(const f16x8*)&s_wfh[pr][ks * 32 + q * 8];
                const f16x8 bh = *(const f16x8*)&wh[((ks * 4 + wid) * 64 + lane) * 8];
                acc = __builtin_amdgcn_mfma_f32_16x16x32_f16(ah, bh, acc, 0, 0, 0);
            }
        }
        // D rows 0..7 = points (rows 8..15 duplicates); direct coalesced store
        if (q < 2) {
#pragma unroll
            for (int r = 0; r < 4; r++)
                out[(base + 4 * q + r) * D + wid * 16 + c] = acc[r];
        }
    }
}

extern "C" void kernel_launch(void* const* d_in, const int* in_sizes, int n_in,
                              void* d_out, int out_size, void* d_ws, size_t ws_size,
                              hipStream_t stream) {
    const float* q   = (const float*)d_in[0];
    const float* s   = (const float*)d_in[1];
    const int*   nb  = (const int*)  d_in[2];
    const float* x   = (const float*)d_in[3];
    const float* kp  = (const float*)d_in[4];
    const float* ow  = (const float*)d_in[5];
    const float* ob  = (const float*)d_in[6];
    const float* w   = (const float*)d_in[7];
    float* out = (float*)d_out;

    unsigned*       xw  = (unsigned*)d_ws;                            // 12,800,000 B
    unsigned short* owh = (unsigned short*)((char*)d_ws + 12800000);  //     98,304 B
    unsigned short* owl = (unsigned short*)((char*)d_ws + 12898304);  //     98,304 B
    unsigned short* wh  = (unsigned short*)((char*)d_ws + 12996608);  //    122,880 B

    prep_all<<<3557, 256, 0, stream>>>(x, ow, w, xw, owh, owl, wh);
    kpconv_deform<<<N_PTS / P, 256, 0, stream>>>(q, s, nb, kp, ob,
                                                 xw, owh, owl, wh, out);
}

// Round 2
// 194.019 us; speedup vs baseline: 1.0680x; 1.0026x over previous
//
#include <hip/hip_runtime.h>

#define N_PTS 50000
#define M 32
#define KP 15
#define D 64
#define E1 45
#define P 8
#define WFS 1048   // wfh plane row stride (ushorts): >=1024 enum slots
#define AWR 36     // aw row stride (ushorts): 18 dwords -> conflict-free b128 frags
#define AWP 576    // aw plane size (16 rows * 36)
#define AWB 1152   // per-point region stride in bufB (hi plane + lo plane)

typedef __attribute__((ext_vector_type(8))) _Float16 f16x8;
typedef __attribute__((ext_vector_type(4))) float    f32x4;
typedef __attribute__((ext_vector_type(2))) _Float16 f16x2;
typedef __attribute__((ext_vector_type(2))) __fp16   fp16v2;   // builtin return type

__device__ __forceinline__ unsigned pkrtz(float a, float b) {   // packed fp16 RTZ
    union { fp16v2 v; unsigned u; } x;
    x.v = __builtin_amdgcn_cvt_pkrtz(a, b);
    return x.u;
}
__device__ __forceinline__ unsigned pkrne(float a, float b) {   // packed fp16 RNE
    union { f16x2 v; unsigned u; } x;
    x.v[0] = (_Float16)a; x.v[1] = (_Float16)b; return x.u;
}
__device__ __forceinline__ float h2f(unsigned bits16) {
    union { unsigned short s; _Float16 h; } x; x.s = (unsigned short)bits16;
    return (float)x.h;
}
// compensated fp16 split of a pair: hu = packed hi (RTZ), lu = packed residual
__device__ __forceinline__ void split2h(float a, float b, unsigned& hu, unsigned& lu) {
    hu = pkrtz(a, b);
    const float ra = a - h2f(hu & 0xffffu);
    const float rb = b - h2f(hu >> 16);
    lu = pkrtz(ra, rb);
}
// packed single value split: lo16 = fp16 hi (RNE), hi16 = fp16 residual
__device__ __forceinline__ unsigned splitpk1(float v) {
    const _Float16 h = (_Float16)v;
    const _Float16 l = (_Float16)(v - (float)h);
    union { f16x2 v2; unsigned u; } x; x.v2[0] = h; x.v2[1] = l; return x.u;
}
__device__ __forceinline__ unsigned u4c(const uint4 v, const int t) {
    return (t == 0) ? v.x : (t == 1) ? v.y : (t == 2) ? v.z : v.w;
}

#if defined(__HIP_DEVICE_COMPILE__) && __has_builtin(__builtin_amdgcn_perm)
__device__ __forceinline__ unsigned permb(unsigned a, unsigned b, unsigned sel) {
    return __builtin_amdgcn_perm(a, b, sel);
}
#else
__device__ __forceinline__ unsigned permb(unsigned a, unsigned b, unsigned sel) {
    if (sel == 0x05040100u) return (b & 0xffffu) | (a << 16);
    return (b >> 16) | (a & 0xffff0000u);
}
#endif

// ---------------- fused prep (one launch; writes d_ws) -----------------------
// blocks [0,3125): x -> packed {f16 hi, f16 residual} dwords, TRANSPOSED row
//     layout: xw[n*64 + c*4 + t] holds x[n][t*16+c]  (c=0..15, t=0..3)
//     -> ph2 lane (c) fetches all 4 t as one dwordx4
// blocks [3125,3317): ow -> owh/owl fp16 planes; pos swizzle:
//     orig = pos ^ (((pos>>6)&3)<<2); d = orig>>4, k = orig&15 (zero pad k==15/e>=45)
// blocks [3317,3557): w -> wh single fp16 plane; pos = k*64+dsw, d = dsw ^ ((k&7)<<3)
__global__ void prep_all(const float* __restrict__ x, const float* __restrict__ ow,
                         const float* __restrict__ w, unsigned* __restrict__ xw,
                         unsigned short* __restrict__ owh, unsigned short* __restrict__ owl,
                         unsigned short* __restrict__ wh)
{
    const int b = blockIdx.x, tid = threadIdx.x;
    if (b < 3125) {
        const int i = b * 256 + tid;                 // float4 index
        const float4 v = ((const float4*)x)[i];
        const int e0 = i * 4;
        const int n = e0 >> 6, d0 = e0 & 63;
        const int t = d0 >> 4, c0 = d0 & 15;         // 4 consecutive c, same t
        unsigned* dst = xw + n * 64 + t;
        dst[(c0 + 0) * 4] = splitpk1(v.x);
        dst[(c0 + 1) * 4] = splitpk1(v.y);
        dst[(c0 + 2) * 4] = splitpk1(v.z);
        dst[(c0 + 3) * 4] = splitpk1(v.w);
    } else if (b < 3317) {
        const int t = (b - 3125) * 256 + tid;               // [0, 49152)
        const int j = t & 7, lane = (t >> 3) & 63, rest = t >> 9;
        const int nt = rest % 3, ks = rest / 3;
        const int q = lane >> 4, c = lane & 15;
        const int pos  = ks * 32 + q * 8 + j;
        const int orig = pos ^ (((pos >> 6) & 3) << 2);
        const int d = orig >> 4, k = orig & 15, e = nt * 16 + c;
        const float v = (k < KP && e < E1) ? ow[k * (D * E1) + d * E1 + e] : 0.f;
        const unsigned u = splitpk1(v);
        owh[t] = (unsigned short)u;
        owl[t] = (unsigned short)(u >> 16);
    } else {
        const int t = (b - 3317) * 256 + tid;               // [0, 61440)
        const int j = t & 7, lane = (t >> 3) & 63, rest = t >> 9;
        const int nt = rest & 3, ks = rest >> 2;            // ks in [0,30)
        const int q = lane >> 4, c = lane & 15;
        const int pos = ks * 32 + q * 8 + j;                // [0,960)
        const int k = pos >> 6, dsw = pos & 63;
        const int d = dsw ^ ((k & 7) << 3);
        const int e = nt * 16 + c;
        union { _Float16 h; unsigned short s; } cv;
        cv.h = (_Float16)w[k * (D * D) + d * D + e];        // RNE single fp16
        wh[t] = cv.s;
    }
}

__global__ __launch_bounds__(256, 4) void kpconv_deform(
    const float* __restrict__ qpts, const float* __restrict__ spts,
    const int*   __restrict__ nbrs, const float* __restrict__ kpts,
    const float* __restrict__ obias,
    const unsigned* __restrict__ xw,
    const unsigned short* __restrict__ owh, const unsigned short* __restrict__ owl,
    const unsigned short* __restrict__ wh,
    float* __restrict__ out)
{
    __shared__ int   s_nbr[P][M];
    __shared__ float s_kp[KP][3];
    __shared__ float s_q[P][3];
    __shared__ float s_off[P][E1];
    __shared__ unsigned s_act[4];
    // wfh plane: ph2->ph3 compensated-hi pair enum (1024); ph6->ph7 single, k*64+dsw
    __shared__ __align__(16) unsigned short s_wfh[P][WFS];
    // bufB multi-use (all transitions wave-private per point or barrier-fenced):
    //   ph1->ph2: aw pair planes at p*AWB (hi) / p*AWB+AWP (lo), row stride AWR=36
    //             -> b128 fragment reads conflict-free (18-dword row stride)
    //   ph2->ph3: wfl residual plane, 1024 slots at p*AWB, XOR-swz by (p&7)<<3
    //   ph3->red: s_part3 partials (after in-ph3 barrier — wfl dead by then)
    //   ph5->ph6: aw hi plane (p*AWB)
    __shared__ __align__(16) char s_bufB[P * AWB * 2];                      // 18432 B
    unsigned short* s_awB = (unsigned short*)s_bufB;
    float (*s_part3)[16][49] = (float(*)[16][49])s_bufB;                    // 12544 B

    const int tid  = threadIdx.x;
    const int base = blockIdx.x * P;
    const int lane = tid & 63;
    const int wid  = tid >> 6;
    const int q    = lane >> 4, c = lane & 15;
    const int pg   = tid >> 5, mg = tid & 31;   // (p,m) mapping for ph1/ph5
    // wave w's ph1/ph5 points {2w,2w+1} == its ph2/ph6 consumers -> no barrier needed

    float nbx, nby, nbz;   // centered neighbor coords, live ph1->ph5
    f16x8 fbh[2][4];       // cached x hi fragments (ph2 -> ph6)

    if (tid < KP * 3) ((float*)s_kp)[tid] = kpts[tid];
    if (tid < P * 3)  ((float*)s_q)[tid]  = qpts[base * 3 + tid];
    __syncthreads();

    // ---- ph1: gather, centered nb, aw1 -> compensated fp16 planes [p][k*AWR+m] ----
    {
        const int ni = nbrs[(base + pg) * M + mg];
        s_nbr[pg][mg] = ni;
        nbx = spts[ni * 3 + 0] - s_q[pg][0];
        nby = spts[ni * 3 + 1] - s_q[pg][1];
        nbz = spts[ni * 3 + 2] - s_q[pg][2];
        float av[16];
        av[15] = 0.f;                               // pad row -> exact zeros
#pragma unroll
        for (int k = 0; k < KP; k++) {
            const float dx = nbx - s_kp[k][0];
            const float dy = nby - s_kp[k][1];
            const float dz = nbz - s_kp[k][2];
            av[k] = fmaxf(1.0f - sqrtf(dx * dx + dy * dy + dz * dz), 0.f);
        }
        const int awb = pg * AWB + mg;
#pragma unroll
        for (int k2 = 0; k2 < 16; k2 += 2) {
            unsigned hu, lu; split2h(av[k2], av[k2 + 1], hu, lu);
            s_awB[awb + k2 * AWR]             = (unsigned short)hu;
            s_awB[awb + (k2 + 1) * AWR]       = (unsigned short)(hu >> 16);
            s_awB[awb + AWP + k2 * AWR]       = (unsigned short)lu;
            s_awB[awb + AWP + (k2 + 1) * AWR] = (unsigned short)(lu >> 16);
        }
    }
    // no barrier: ph2 wave reads only its own writes (lgkmcnt ordering)

    // ---- ph2: wf1 via compensated f16 MFMA; cache x hi fragments ----
    // NOTE: aw[p] reads precede wfl[p] writes (same region, same wave, program
    // order preserved by may-alias LDS ops) -> safe in-place reuse.
    {
        const int hc = c >> 2;
        const uint4* __restrict__ xwq = (const uint4*)xw;
#pragma unroll
        for (int pi = 0; pi < 2; pi++) {
            const int p = 2 * wid + pi;
            const int pswz = p << 3;
            const int ab = p * AWB + (lane & 15) * AWR + q * 8;
            const f16x8 ah = *(const f16x8*)&s_awB[ab];
            const f16x8 al = *(const f16x8*)&s_awB[ab + AWP];
            uint4 g4[8];                             // row-slices: {t0..t3} per (j,c)
#pragma unroll
            for (int j = 0; j < 8; j++)
                g4[j] = xwq[s_nbr[p][q * 8 + j] * 16 + c];
#pragma unroll
            for (int t = 0; t < 4; t++) {
                union { f16x8 v; unsigned u[4]; } bh, bl;
#pragma unroll
                for (int jj = 0; jj < 4; jj++) {    // perm-unpack hi/lo planes
                    const unsigned ga = u4c(g4[2 * jj + 1], t);
                    const unsigned gb = u4c(g4[2 * jj], t);
                    bh.u[jj] = permb(ga, gb, 0x05040100u);
                    bl.u[jj] = permb(ga, gb, 0x07060302u);
                }
                fbh[pi][t] = bh.v;                   // cache hi for ph6
                f32x4 dacc = {0.f, 0.f, 0.f, 0.f};
                dacc = __builtin_amdgcn_mfma_f32_16x16x32_f16(ah, bh.v, dacc, 0, 0, 0);
                dacc = __builtin_amdgcn_mfma_f32_16x16x32_f16(ah, bl.v, dacc, 0, 0, 0);
                dacc = __builtin_amdgcn_mfma_f32_16x16x32_f16(al, bh.v, dacc, 0, 0, 0);
                unsigned h01, l01, h23, l23;
                split2h(dacc[0], dacc[1], h01, l01);
                split2h(dacc[2], dacc[3], h23, l23);
                // swizzled enum: pos = (t*16+c)*16 + 4*(q^hc) (+r)
                const int eb = (t * 16 + c) * 16 + 4 * (q ^ hc);
                *(uint2*)&s_wfh[p][eb] = make_uint2(h01, h23);
                *(uint2*)&s_awB[p * AWB + (eb ^ pswz)] = make_uint2(l01, l23);
            }
        }
    }
    __syncthreads();

    // ---- ph3: offsets via compensated f16 MFMA, contraction split over 4 waves ----
    {
        const int pr = lane & 7;                     // A rows 8..15 duplicate points 0..7
        const int prswz = pr << 3;
        f32x4 acc0 = {0,0,0,0}, acc1 = {0,0,0,0}, acc2 = {0,0,0,0};
#pragma unroll
        for (int s = 0; s < 8; s++) {
            const int ks = wid * 8 + s;
            const f16x8 ah = *(const f16x8*)&s_wfh[pr][ks * 32 + q * 8];
            const f16x8 al = *(const f16x8*)&s_awB[pr * AWB + ((ks * 32 + q * 8) ^ prswz)];
#pragma unroll
            for (int nt = 0; nt < 3; nt++) {
                const int f = ((ks * 3 + nt) * 64 + lane) * 8;
                const f16x8 bh = *(const f16x8*)&owh[f];
                const f16x8 bl = *(const f16x8*)&owl[f];
                f32x4* acc = (nt == 0) ? &acc0 : (nt == 1) ? &acc1 : &acc2;
                *acc = __builtin_amdgcn_mfma_f32_16x16x32_f16(ah, bh, *acc, 0, 0, 0);
                *acc = __builtin_amdgcn_mfma_f32_16x16x32_f16(ah, bl, *acc, 0, 0, 0);
                *acc = __builtin_amdgcn_mfma_f32_16x16x32_f16(al, bh, *acc, 0, 0, 0);
            }
        }
        __syncthreads();   // wfl (bufB) about to be clobbered by s_part3
#pragma unroll
        for (int r = 0; r < 4; r++) {
            s_part3[wid][4 * q + r][0 * 16 + c] = acc0[r];
            s_part3[wid][4 * q + r][1 * 16 + c] = acc1[r];
            s_part3[wid][4 * q + r][2 * 16 + c] = acc2[r];
        }
    }
    __syncthreads();

    // ---- reduce K-partials + bias -> offsets (fp32) ----
    for (int idx = tid; idx < P * E1; idx += 256) {
        const int p = idx / E1, e = idx % E1;
        s_off[p][e] = s_part3[0][p][e] + s_part3[1][p][e] +
                      s_part3[2][p][e] + s_part3[3][p][e] + obias[e];
    }
    __syncthreads();

    // ---- ph5: aw2 (deformed) -> single fp16 plane (RNE) + joint wave mask ----
    {
        unsigned pmask = 0;
        float av[16];
        av[15] = 0.f;
#pragma unroll
        for (int k = 0; k < KP; k++) {
            const float kx = s_kp[k][0] + s_off[pg][3 * k + 0];
            const float ky = s_kp[k][1] + s_off[pg][3 * k + 1];
            const float kz = s_kp[k][2] + s_off[pg][3 * k + 2];
            const float dx = nbx - kx, dy = nby - ky, dz = nbz - kz;
            av[k] = fmaxf(1.0f - sqrtf(dx * dx + dy * dy + dz * dz), 0.f);
            pmask |= (__ballot(av[k] > 0.f) ? 1u : 0u) << k;   // union of wave's 2 pts
        }
        const int awb = pg * AWB + mg;
#pragma unroll
        for (int k2 = 0; k2 < 16; k2 += 2) {
            const unsigned hu = pkrne(av[k2], av[k2 + 1]);
            s_awB[awb + k2 * AWR]       = (unsigned short)hu;
            s_awB[awb + (k2 + 1) * AWR] = (unsigned short)(hu >> 16);
        }
        if (lane == 0) s_act[wid] = pmask;
    }
    // no barrier: ph6 wave reads only its own aw writes; s_act read after next barrier

    // ---- ph6: wf2 via single f16 MFMA, operands swapped (D[d][k]) ----
    {
#pragma unroll
        for (int pi = 0; pi < 2; pi++) {
            const int p = 2 * wid + pi;
            const f16x8 awh_f = *(const f16x8*)&s_awB[p * AWB + (lane & 15) * AWR + q * 8];
#pragma unroll
            for (int t = 0; t < 4; t++) {
                f32x4 dacc = {0.f, 0.f, 0.f, 0.f};
                dacc = __builtin_amdgcn_mfma_f32_16x16x32_f16(fbh[pi][t], awh_f, dacc, 0, 0, 0);
                // wf2[k=c][d = t*16+4q+r] single fp16 (RNE); dsw keeps 4-runs
                const unsigned u01 = pkrne(dacc[0], dacc[1]);
                const unsigned u23 = pkrne(dacc[2], dacc[3]);
                const int dsw = (t * 16 + 4 * q) ^ ((c & 7) << 3);
                *(uint2*)&s_wfh[p][c * 64 + dsw] = make_uint2(u01, u23);
            }
        }
    }
    __syncthreads();

    const unsigned u2 = s_act[0] | s_act[1] | s_act[2] | s_act[3];

    // ---- ph7: output via single f16 MFMA over active k; wave = e-tile ----
    {
        const int pr = lane & 7;                    // A rows 8..15 duplicate points 0..7
        f32x4 acc = {0.f, 0.f, 0.f, 0.f};
#pragma unroll
        for (int k = 0; k < KP; k++) {
            if (!((u2 >> k) & 1)) continue;
#pragma unroll
            for (int kk = 0; kk < 2; kk++) {
                const int ks = k * 2 + kk;          // pos chunk: k = ks>>1
                const f16x8 ah = *(const f16x8*)&s_wfh[pr][ks * 32 + q * 8];
                const f16x8 bh = *(const f16x8*)&wh[((ks * 4 + wid) * 64 + lane) * 8];
                acc = __builtin_amdgcn_mfma_f32_16x16x32_f16(ah, bh, acc, 0, 0, 0);
            }
        }
        // D rows 0..7 = points (rows 8..15 duplicates); direct coalesced store
        if (q < 2) {
#pragma unroll
            for (int r = 0; r < 4; r++)
                out[(base + 4 * q + r) * D + wid * 16 + c] = acc[r];
        }
    }
}

extern "C" void kernel_launch(void* const* d_in, const int* in_sizes, int n_in,
                              void* d_out, int out_size, void* d_ws, size_t ws_size,
                              hipStream_t stream) {
    const float* q   = (const float*)d_in[0];
    const float* s   = (const float*)d_in[1];
    const int*   nb  = (const int*)  d_in[2];
    const float* x   = (const float*)d_in[3];
    const float* kp  = (const float*)d_in[4];
    const float* ow  = (const float*)d_in[5];
    const float* ob  = (const float*)d_in[6];
    const float* w   = (const float*)d_in[7];
    float* out = (float*)d_out;

    unsigned*       xw  = (unsigned*)d_ws;                            // 12,800,000 B
    unsigned short* owh = (unsigned short*)((char*)d_ws + 12800000);  //     98,304 B
    unsigned short* owl = (unsigned short*)((char*)d_ws + 12898304);  //     98,304 B
    unsigned short* wh  = (unsigned short*)((char*)d_ws + 12996608);  //    122,880 B

    prep_all<<<3557, 256, 0, stream>>>(x, ow, w, xw, owh, owl, wh);
    kpconv_deform<<<N_PTS / P, 256, 0, stream>>>(q, s, nb, kp, ob,
                                                 xw, owh, owl, wh, out);
}

// Round 3
// 184.289 us; speedup vs baseline: 1.1244x; 1.0528x over previous
//
#include <hip/hip_runtime.h>

#define N_PTS 50000
#define M 32
#define KP 15
#define D 64
#define E1 45
#define P 8
#define WFS 1048   // wfh plane row stride (ushorts): >=1024 enum slots
#define AWR 36     // aw row stride (ushorts): 18 dwords -> conflict-free b128 frags
#define AWP 576    // aw plane size (16 rows * 36)
#define AWB 1152   // per-point region stride in bufB (hi plane + lo plane)

typedef __attribute__((ext_vector_type(8))) _Float16 f16x8;
typedef __attribute__((ext_vector_type(4))) float    f32x4;
typedef __attribute__((ext_vector_type(2))) _Float16 f16x2;
typedef __attribute__((ext_vector_type(2))) __fp16   fp16v2;   // builtin return type

__device__ __forceinline__ unsigned pkrtz(float a, float b) {   // packed fp16 RTZ
    union { fp16v2 v; unsigned u; } x;
    x.v = __builtin_amdgcn_cvt_pkrtz(a, b);
    return x.u;
}
__device__ __forceinline__ unsigned pkrne(float a, float b) {   // packed fp16 RNE
    union { f16x2 v; unsigned u; } x;
    x.v[0] = (_Float16)a; x.v[1] = (_Float16)b; return x.u;
}
__device__ __forceinline__ float h2f(unsigned bits16) {
    union { unsigned short s; _Float16 h; } x; x.s = (unsigned short)bits16;
    return (float)x.h;
}
// compensated fp16 split of a pair: hu = packed hi (RTZ), lu = packed residual
__device__ __forceinline__ void split2h(float a, float b, unsigned& hu, unsigned& lu) {
    hu = pkrtz(a, b);
    const float ra = a - h2f(hu & 0xffffu);
    const float rb = b - h2f(hu >> 16);
    lu = pkrtz(ra, rb);
}
// packed single value split: lo16 = fp16 hi (RNE), hi16 = fp16 residual
__device__ __forceinline__ unsigned splitpk1(float v) {
    const _Float16 h = (_Float16)v;
    const _Float16 l = (_Float16)(v - (float)h);
    union { f16x2 v2; unsigned u; } x; x.v2[0] = h; x.v2[1] = l; return x.u;
}
__device__ __forceinline__ unsigned u4c(const uint4 v, const int t) {
    return (t == 0) ? v.x : (t == 1) ? v.y : (t == 2) ? v.z : v.w;
}

#if defined(__HIP_DEVICE_COMPILE__) && __has_builtin(__builtin_amdgcn_perm)
__device__ __forceinline__ unsigned permb(unsigned a, unsigned b, unsigned sel) {
    return __builtin_amdgcn_perm(a, b, sel);
}
#else
__device__ __forceinline__ unsigned permb(unsigned a, unsigned b, unsigned sel) {
    if (sel == 0x05040100u) return (b & 0xffffu) | (a << 16);
    return (b >> 16) | (a & 0xffff0000u);
}
#endif

// ---------------- fused prep (one launch; writes d_ws) -----------------------
// blocks [0,3125): x -> packed {f16 hi, f16 residual} dwords, TRANSPOSED row
//     layout: xw[n*64 + c*4 + t] holds x[n][t*16+c]  (c=0..15, t=0..3)
//     -> ph2 lane (c) fetches all 4 t as one dwordx4
// blocks [3125,3317): ow -> owh/owl fp16 planes; pos swizzle:
//     orig = pos ^ (((pos>>6)&3)<<2); d = orig>>4, k = orig&15 (zero pad k==15/e>=45)
// blocks [3317,3557): w -> wh single fp16 plane; pos = k*64+dsw, d = dsw ^ ((k&7)<<3)
__global__ void prep_all(const float* __restrict__ x, const float* __restrict__ ow,
                         const float* __restrict__ w, unsigned* __restrict__ xw,
                         unsigned short* __restrict__ owh, unsigned short* __restrict__ owl,
                         unsigned short* __restrict__ wh)
{
    const int b = blockIdx.x, tid = threadIdx.x;
    if (b < 3125) {
        const int i = b * 256 + tid;                 // float4 index
        const float4 v = ((const float4*)x)[i];
        const int e0 = i * 4;
        const int n = e0 >> 6, d0 = e0 & 63;
        const int t = d0 >> 4, c0 = d0 & 15;         // 4 consecutive c, same t
        unsigned* dst = xw + n * 64 + t;
        dst[(c0 + 0) * 4] = splitpk1(v.x);
        dst[(c0 + 1) * 4] = splitpk1(v.y);
        dst[(c0 + 2) * 4] = splitpk1(v.z);
        dst[(c0 + 3) * 4] = splitpk1(v.w);
    } else if (b < 3317) {
        const int t = (b - 3125) * 256 + tid;               // [0, 49152)
        const int j = t & 7, lane = (t >> 3) & 63, rest = t >> 9;
        const int nt = rest % 3, ks = rest / 3;
        const int q = lane >> 4, c = lane & 15;
        const int pos  = ks * 32 + q * 8 + j;
        const int orig = pos ^ (((pos >> 6) & 3) << 2);
        const int d = orig >> 4, k = orig & 15, e = nt * 16 + c;
        const float v = (k < KP && e < E1) ? ow[k * (D * E1) + d * E1 + e] : 0.f;
        const unsigned u = splitpk1(v);
        owh[t] = (unsigned short)u;
        owl[t] = (unsigned short)(u >> 16);
    } else {
        const int t = (b - 3317) * 256 + tid;               // [0, 61440)
        const int j = t & 7, lane = (t >> 3) & 63, rest = t >> 9;
        const int nt = rest & 3, ks = rest >> 2;            // ks in [0,30)
        const int q = lane >> 4, c = lane & 15;
        const int pos = ks * 32 + q * 8 + j;                // [0,960)
        const int k = pos >> 6, dsw = pos & 63;
        const int d = dsw ^ ((k & 7) << 3);
        const int e = nt * 16 + c;
        union { _Float16 h; unsigned short s; } cv;
        cv.h = (_Float16)w[k * (D * D) + d * D + e];        // RNE single fp16
        wh[t] = cv.s;
    }
}

__global__ __launch_bounds__(256, 4) void kpconv_deform(
    const float* __restrict__ qpts, const float* __restrict__ spts,
    const int*   __restrict__ nbrs, const float* __restrict__ kpts,
    const float* __restrict__ obias,
    const unsigned* __restrict__ xw,
    const unsigned short* __restrict__ owh, const unsigned short* __restrict__ owl,
    const unsigned short* __restrict__ wh,
    float* __restrict__ out)
{
    __shared__ int   s_nbr[P][M];
    __shared__ float s_q[P][3];
    __shared__ float s_off[P][E1];
    __shared__ unsigned s_act[4];
    // wfh plane: ph2->ph3 compensated-hi pair enum (1024); ph6->ph7 single, k*64+dsw
    __shared__ __align__(16) unsigned short s_wfh[P][WFS];
    // bufB multi-use (all transitions wave-private per point or barrier-fenced):
    //   ph1->ph2: aw pair planes at p*AWB (hi) / p*AWB+AWP (lo), row stride AWR=36
    //   ph2->ph3: wfl residual plane, 1024 slots at p*AWB, XOR-swz by (p&7)<<3
    //   ph3->red: s_part3 partials (after in-ph3 barrier — wfl dead by then)
    //   ph5->ph6: aw hi plane (p*AWB)
    __shared__ __align__(16) char s_bufB[P * AWB * 2];                      // 18432 B
    unsigned short* s_awB = (unsigned short*)s_bufB;
    float (*s_part3)[16][49] = (float(*)[16][49])s_bufB;                    // 12544 B

    const int tid  = threadIdx.x;
    const int base = blockIdx.x * P;
    const int lane = tid & 63;
    const int wid  = tid >> 6;
    const int q    = lane >> 4, c = lane & 15;
    const int pg   = tid >> 5, mg = tid & 31;   // (p,m) mapping for ph1/ph5
    // wave w's ph1/ph5 points {2w,2w+1} == its ph2/ph6 consumers -> no barrier needed

    float nbx, nby, nbz;   // centered neighbor coords, live ph1->ph5
    f16x8 fbh[2][4];       // cached x hi fragments (ph2 -> ph6)
    uint4 g4[2][8];        // hoisted x-row gathers (issued ph1, consumed ph2)

    if (tid < P * 3)  ((float*)s_q)[tid]  = qpts[base * 3 + tid];
    __syncthreads();

    // ---- ph1: nbr gather + EARLY x-row gather issue; geometry; aw1 planes ----
    {
        const int ni = nbrs[(base + pg) * M + mg];
        s_nbr[pg][mg] = ni;
        const float sx = spts[ni * 3 + 0];
        const float sy = spts[ni * 3 + 1];
        const float sz = spts[ni * 3 + 2];
        // issue this wave's 16 x-row gathers NOW; latency hides under geometry.
        // s_nbr written above by this same wave -> lgkmcnt ordering, no barrier.
        const uint4* __restrict__ xwq = (const uint4*)xw;
#pragma unroll
        for (int pi = 0; pi < 2; pi++)
#pragma unroll
            for (int j = 0; j < 8; j++)
                g4[pi][j] = xwq[s_nbr[2 * wid + pi][q * 8 + j] * 16 + c];
        nbx = sx - s_q[pg][0];
        nby = sy - s_q[pg][1];
        nbz = sz - s_q[pg][2];
        float av[16];
        av[15] = 0.f;                               // pad row -> exact zeros
#pragma unroll
        for (int k = 0; k < KP; k++) {              // kpts uniform -> scalar loads
            const float dx = nbx - kpts[k * 3 + 0];
            const float dy = nby - kpts[k * 3 + 1];
            const float dz = nbz - kpts[k * 3 + 2];
            av[k] = fmaxf(1.0f - sqrtf(dx * dx + dy * dy + dz * dz), 0.f);
        }
        const int awb = pg * AWB + mg;
#pragma unroll
        for (int k2 = 0; k2 < 16; k2 += 2) {
            unsigned hu, lu; split2h(av[k2], av[k2 + 1], hu, lu);
            s_awB[awb + k2 * AWR]             = (unsigned short)hu;
            s_awB[awb + (k2 + 1) * AWR]       = (unsigned short)(hu >> 16);
            s_awB[awb + AWP + k2 * AWR]       = (unsigned short)lu;
            s_awB[awb + AWP + (k2 + 1) * AWR] = (unsigned short)(lu >> 16);
        }
    }
    // no barrier: ph2 wave reads only its own writes (lgkmcnt ordering)

    // ---- ph2: wf1 via compensated f16 MFMA; cache x hi fragments ----
    // NOTE: aw[p] reads precede wfl[p] writes (same region, same wave, program
    // order preserved by may-alias LDS ops) -> safe in-place reuse.
    {
        const int hc = c >> 2;
#pragma unroll
        for (int pi = 0; pi < 2; pi++) {
            const int p = 2 * wid + pi;
            const int pswz = p << 3;
            const int ab = p * AWB + (lane & 15) * AWR + q * 8;
            const f16x8 ah = *(const f16x8*)&s_awB[ab];
            const f16x8 al = *(const f16x8*)&s_awB[ab + AWP];
#pragma unroll
            for (int t = 0; t < 4; t++) {
                union { f16x8 v; unsigned u[4]; } bh, bl;
#pragma unroll
                for (int jj = 0; jj < 4; jj++) {    // perm-unpack hi/lo planes
                    const unsigned ga = u4c(g4[pi][2 * jj + 1], t);
                    const unsigned gb = u4c(g4[pi][2 * jj], t);
                    bh.u[jj] = permb(ga, gb, 0x05040100u);
                    bl.u[jj] = permb(ga, gb, 0x07060302u);
                }
                fbh[pi][t] = bh.v;                   // cache hi for ph6
                f32x4 dacc = {0.f, 0.f, 0.f, 0.f};
                dacc = __builtin_amdgcn_mfma_f32_16x16x32_f16(ah, bh.v, dacc, 0, 0, 0);
                dacc = __builtin_amdgcn_mfma_f32_16x16x32_f16(ah, bl.v, dacc, 0, 0, 0);
                dacc = __builtin_amdgcn_mfma_f32_16x16x32_f16(al, bh.v, dacc, 0, 0, 0);
                unsigned h01, l01, h23, l23;
                split2h(dacc[0], dacc[1], h01, l01);
                split2h(dacc[2], dacc[3], h23, l23);
                // swizzled enum: pos = (t*16+c)*16 + 4*(q^hc) (+r)
                const int eb = (t * 16 + c) * 16 + 4 * (q ^ hc);
                *(uint2*)&s_wfh[p][eb] = make_uint2(h01, h23);
                *(uint2*)&s_awB[p * AWB + (eb ^ pswz)] = make_uint2(l01, l23);
            }
        }
    }
    __syncthreads();

    // ---- ph3: offsets via hi/lo-packed f16 MFMA, contraction split over 4 waves ----
    // A rows 0..7 = wfh(point pr), rows 8..15 = wfl(point pr): 2 MFMAs compute
    // (ah+al)*(bh+bl); row p and p+8 of D are summed in the reduce.
    {
        const int pr = lane & 7;
        const int rsel = (lane >> 3) & 1;            // 0: hi rows, 1: lo rows
        const int prswz = pr << 3;
        f32x4 acc0 = {0,0,0,0}, acc1 = {0,0,0,0}, acc2 = {0,0,0,0};
#pragma unroll
        for (int s = 0; s < 8; s++) {
            const int ks = wid * 8 + s;
            const int off = ks * 32 + q * 8;
            const unsigned short* aptr = rsel ? &s_awB[pr * AWB + (off ^ prswz)]
                                              : &s_wfh[pr][off];
            const f16x8 a_hl = *(const f16x8*)aptr;
#pragma unroll
            for (int nt = 0; nt < 3; nt++) {
                const int f = ((ks * 3 + nt) * 64 + lane) * 8;
                const f16x8 bh = *(const f16x8*)&owh[f];
                const f16x8 bl = *(const f16x8*)&owl[f];
                f32x4* acc = (nt == 0) ? &acc0 : (nt == 1) ? &acc1 : &acc2;
                *acc = __builtin_amdgcn_mfma_f32_16x16x32_f16(a_hl, bh, *acc, 0, 0, 0);
                *acc = __builtin_amdgcn_mfma_f32_16x16x32_f16(a_hl, bl, *acc, 0, 0, 0);
            }
        }
        __syncthreads();   // wfl (bufB) about to be clobbered by s_part3
#pragma unroll
        for (int r = 0; r < 4; r++) {
            s_part3[wid][4 * q + r][0 * 16 + c] = acc0[r];
            s_part3[wid][4 * q + r][1 * 16 + c] = acc1[r];
            s_part3[wid][4 * q + r][2 * 16 + c] = acc2[r];
        }
    }
    __syncthreads();

    // ---- reduce K-partials (hi rows + lo rows) + bias -> offsets (fp32) ----
    for (int idx = tid; idx < P * E1; idx += 256) {
        const int p = idx / E1, e = idx % E1;
        float v = obias[e];
#pragma unroll
        for (int w4 = 0; w4 < 4; w4++)
            v += s_part3[w4][p][e] + s_part3[w4][p + 8][e];
        s_off[p][e] = v;
    }
    __syncthreads();

    // ---- ph5: aw2 (deformed) -> single fp16 plane (RNE) + joint wave mask ----
    {
        unsigned pmask = 0;
        float av[16];
        av[15] = 0.f;
#pragma unroll
        for (int k = 0; k < KP; k++) {
            const float kx = kpts[k * 3 + 0] + s_off[pg][3 * k + 0];
            const float ky = kpts[k * 3 + 1] + s_off[pg][3 * k + 1];
            const float kz = kpts[k * 3 + 2] + s_off[pg][3 * k + 2];
            const float dx = nbx - kx, dy = nby - ky, dz = nbz - kz;
            av[k] = fmaxf(1.0f - sqrtf(dx * dx + dy * dy + dz * dz), 0.f);
            pmask |= (__ballot(av[k] > 0.f) ? 1u : 0u) << k;   // union of wave's 2 pts
        }
        const int awb = pg * AWB + mg;
#pragma unroll
        for (int k2 = 0; k2 < 16; k2 += 2) {
            const unsigned hu = pkrne(av[k2], av[k2 + 1]);
            s_awB[awb + k2 * AWR]       = (unsigned short)hu;
            s_awB[awb + (k2 + 1) * AWR] = (unsigned short)(hu >> 16);
        }
        if (lane == 0) s_act[wid] = pmask;
    }
    // no barrier: ph6 wave reads only its own aw writes; s_act read after next barrier

    // ---- ph6: wf2 via single f16 MFMA, operands swapped (D[d][k]) ----
    {
#pragma unroll
        for (int pi = 0; pi < 2; pi++) {
            const int p = 2 * wid + pi;
            const f16x8 awh_f = *(const f16x8*)&s_awB[p * AWB + (lane & 15) * AWR + q * 8];
#pragma unroll
            for (int t = 0; t < 4; t++) {
                f32x4 dacc = {0.f, 0.f, 0.f, 0.f};
                dacc = __builtin_amdgcn_mfma_f32_16x16x32_f16(fbh[pi][t], awh_f, dacc, 0, 0, 0);
                // wf2[k=c][d = t*16+4q+r] single fp16 (RNE); dsw keeps 4-runs
                const unsigned u01 = pkrne(dacc[0], dacc[1]);
                const unsigned u23 = pkrne(dacc[2], dacc[3]);
                const int dsw = (t * 16 + 4 * q) ^ ((c & 7) << 3);
                *(uint2*)&s_wfh[p][c * 64 + dsw] = make_uint2(u01, u23);
            }
        }
    }
    __syncthreads();

    const unsigned u2 = s_act[0] | s_act[1] | s_act[2] | s_act[3];

    // ---- ph7: output via single f16 MFMA over active k; wave = e-tile ----
    {
        const int pr = lane & 7;                    // A rows 8..15 duplicate points 0..7
        f32x4 acc = {0.f, 0.f, 0.f, 0.f};
#pragma unroll
        for (int k = 0; k < KP; k++) {
            if (!((u2 >> k) & 1)) continue;
#pragma unroll
            for (int kk = 0; kk < 2; kk++) {
                const int ks = k * 2 + kk;          // pos chunk: k = ks>>1
                const f16x8 ah = *(const f16x8*)&s_wfh[pr][ks * 32 + q * 8];
                const f16x8 bh = *(const f16x8*)&wh[((ks * 4 + wid) * 64 + lane) * 8];
                acc = __builtin_amdgcn_mfma_f32_16x16x32_f16(ah, bh, acc, 0, 0, 0);
            }
        }
        // D rows 0..7 = points (rows 8..15 duplicates); direct coalesced store
        if (q < 2) {
#pragma unroll
            for (int r = 0; r < 4; r++)
                out[(base + 4 * q + r) * D + wid * 16 + c] = acc[r];
        }
    }
}

extern "C" void kernel_launch(void* const* d_in, const int* in_sizes, int n_in,
                              void* d_out, int out_size, void* d_ws, size_t ws_size,
                              hipStream_t stream) {
    const float* q   = (const float*)d_in[0];
    const float* s   = (const float*)d_in[1];
    const int*   nb  = (const int*)  d_in[2];
    const float* x   = (const float*)d_in[3];
    const float* kp  = (const float*)d_in[4];
    const float* ow  = (const float*)d_in[5];
    const float* ob  = (const float*)d_in[6];
    const float* w   = (const float*)d_in[7];
    float* out = (float*)d_out;

    unsigned*       xw  = (unsigned*)d_ws;                            // 12,800,000 B
    unsigned short* owh = (unsigned short*)((char*)d_ws + 12800000);  //     98,304 B
    unsigned short* owl = (unsigned short*)((char*)d_ws + 12898304);  //     98,304 B
    unsigned short* wh  = (unsigned short*)((char*)d_ws + 12996608);  //    122,880 B

    prep_all<<<3557, 256, 0, stream>>>(x, ow, w, xw, owh, owl, wh);
    kpconv_deform<<<N_PTS / P, 256, 0, stream>>>(q, s, nb, kp, ob,
                                                 xw, owh, owl, wh, out);
}